// Round 17
// baseline (139.303 us; speedup 1.0000x reference)
//
#include <hip/hip_runtime.h>
#include <hip/hip_fp16.h>
#include <stdint.h>

#define CBP_D 8192
#define CBP_C 512
#define CBP_W 512
#define ROWS 64          // rows staged per block; lane covers 8 rows (b128)
#define NTHREADS 1024    // 16 waves
#define NSPLIT 4         // 64 row-blocks x 4 = 256 blocks = 1/CU
#define NCAP 80          // pair-list row capacity

// LDS layout (bytes): 128B channel stride. x2 ch 0..512 (ch 512 = zeros),
// then x1 ch 0..512 (ch 512 = zeros). Pair word = (i<<7)|(j<<17).
#define X1OFF 65664      // 513*128
#define ZREL  65536      // zero channel offset within each region (ch 512)
#define LDSSZ 131328     // X1OFF + 513*128
#define PADW  ((512u << 7) | (512u << 17))   // pad: both sides hit zero channels

// ================= precompute (single fused kernel) =================
__global__ __launch_bounds__(512, 2)
void pB_fill(const int* __restrict__ h1, const int* __restrict__ h2,
             int* __restrict__ cnt, int* __restrict__ cntmax,
             uint32_t* __restrict__ pairs) {
    __shared__ int sc[CBP_D];       // h2 histogram
    __shared__ int sb[CBP_D];       // bucket start offsets
    __shared__ int ssum[512];
    __shared__ short sbk[CBP_C];    // bucket-ordered j list
    __shared__ int sh1[CBP_C];
    __shared__ int sh2[CBP_C];
    __shared__ int pc[64][8];
    __shared__ int rawt[64];
    int tid = threadIdx.x;          // 512

    for (int k = tid; k < CBP_D; k += 512) sc[k] = 0;
    sh1[tid] = h1[tid];
    sh2[tid] = h2[tid];
    __syncthreads();
    atomicAdd(&sc[sh2[tid]], 1);
    __syncthreads();
    int base = tid * 16;
    int loc[16]; int s = 0;
#pragma unroll
    for (int k = 0; k < 16; ++k) { loc[k] = sc[base + k]; s += loc[k]; }
    ssum[tid] = s;
    __syncthreads();
    int acc = s;
    for (int off = 1; off < 512; off <<= 1) {
        int add = (tid >= off) ? ssum[tid - off] : 0;
        __syncthreads();
        acc += add; ssum[tid] = acc;
        __syncthreads();
    }
    int excl = acc - s;
#pragma unroll
    for (int k = 0; k < 16; ++k) { sb[base + k] = excl; excl += loc[k]; }
    __syncthreads();
    {
        int h = sh2[tid]; int r = 0;
        for (int j2 = 0; j2 < tid; ++j2) r += (sh2[j2] == h);
        sbk[sb[h] + r] = (short)tid;
    }
    __syncthreads();

    // ---- pair-list build: 8 threads per d, 64 d's per block ----
    int dl = tid >> 3, p = tid & 7;
    int d = blockIdx.x * 64 + dl;
    int i0 = p << 6;
    int cp = 0;
#pragma unroll 4
    for (int i = i0; i < i0 + 64; ++i) cp += sc[(d - sh1[i]) & (CBP_D - 1)];
    pc[dl][p] = cp;
    __syncthreads();
    int off = 0, tot = 0;
#pragma unroll
    for (int p2 = 0; p2 < 8; ++p2) { int v = pc[dl][p2]; off += (p2 < p) ? v : 0; tot += v; }
    uint32_t* pd = pairs + (size_t)d * NCAP;
    int pos = off;
    for (int i = i0; i < i0 + 64; ++i) {
        int t = (d - sh1[i]) & (CBP_D - 1);
        int n = sc[t];
        if (n) {
            int bo = sb[t];
            uint32_t iw = (uint32_t)(i << 7);
            for (int k = 0; k < n; ++k)
                pd[pos++] = iw | ((uint32_t)sbk[bo + k] << 17);
        }
    }
    // pad own list to multiple of 4 (pads -> zero channels)
    int npad = (4 - (tot & 3)) & 3;
    if (p < npad) pd[tot + p] = PADW;
    if (p == 0) { rawt[dl] = tot; cnt[d] = (tot + 3) & ~3; }
    __syncthreads();
    if (p == 0 && (dl & 7) == 0) {
        int omax = 0;
#pragma unroll
        for (int z = 0; z < 8; ++z) omax = max(omax, rawt[dl + z]);
        cntmax[blockIdx.x * 8 + (dl >> 3)] = (omax + 3) & ~3;
    }
}

// ================= main =================

// Group grp (lane>>3) owns d = octb+grp; lane l (lane&7) covers rows 8l..8l+7
// via one ds_read_b128 per operand. Two independent accumulator chains (A/B).
#define PROCA(P) { \
    uint32_t p_ = (P); \
    uint32_t aB_ = (p_ & 0x1FF80u) + baseA; \
    uint32_t bB_ = ((p_ >> 10) & 0x1FF80u) + baseB; \
    uint4 ra_ = *(const uint4*)(xsh + aB_); \
    uint4 rb_ = *(const uint4*)(xsh + bB_); \
    aA01 = __hfma2(*(const __half2*)&ra_.x, *(const __half2*)&rb_.x, aA01); \
    aA23 = __hfma2(*(const __half2*)&ra_.y, *(const __half2*)&rb_.y, aA23); \
    aA45 = __hfma2(*(const __half2*)&ra_.z, *(const __half2*)&rb_.z, aA45); \
    aA67 = __hfma2(*(const __half2*)&ra_.w, *(const __half2*)&rb_.w, aA67); }
#define PROCB(P) { \
    uint32_t p_ = (P); \
    uint32_t aB_ = (p_ & 0x1FF80u) + baseA; \
    uint32_t bB_ = ((p_ >> 10) & 0x1FF80u) + baseB; \
    uint4 ra_ = *(const uint4*)(xsh + aB_); \
    uint4 rb_ = *(const uint4*)(xsh + bB_); \
    aB01 = __hfma2(*(const __half2*)&ra_.x, *(const __half2*)&rb_.x, aB01); \
    aB23 = __hfma2(*(const __half2*)&ra_.y, *(const __half2*)&rb_.y, aB23); \
    aB45 = __hfma2(*(const __half2*)&ra_.z, *(const __half2*)&rb_.z, aB45); \
    aB67 = __hfma2(*(const __half2*)&ra_.w, *(const __half2*)&rb_.w, aB67); }

// One octet (8 consecutive d). Each group's list split into front/back halves
// with independent f16 chains, interleaved 2 iterations per flush (4 chunks,
// 32 independent ds_read_b128 per body) -> 2x ILP on the LDS->fma chain.
// After 3-stage butterfly, lane holds row 8*(lane&7)+(lane>>3), d octb+0..7.
#define OCT(K, DST0, DST1) { \
    int oc_ = (oo << 1) + (K); \
    int octb_ = dbase + (oc_ << 3); \
    int nbmax_ = nmax_cur; \
    int nbown_ = nown_cur; \
    int no_ = (oc_ + 1 < 16) ? oc_ + 1 : 15; \
    nmax_cur = __builtin_amdgcn_readfirstlane(cntmax[(dbase >> 3) + no_]) >> 2; \
    nown_cur = cnt[dbase + (no_ << 3) + grp] >> 2; \
    const uint4* plF_ = (const uint4*)(pairs + (size_t)(octb_ + grp) * NCAP); \
    int nf_ = (nbown_ + 1) >> 1, nbk_ = nbown_ >> 1; \
    const uint4* plB_ = plF_ + nf_; \
    int nfmax_ = (nbmax_ + 1) >> 1; \
    float f0 = 0.f, f1 = 0.f, f2 = 0.f, f3 = 0.f; \
    float f4 = 0.f, f5 = 0.f, f6 = 0.f, f7 = 0.f; \
    int t_ = 0; \
    while (t_ < nfmax_) { \
        __half2 aA01 = __floats2half2_rn(0.f, 0.f); \
        __half2 aA23 = aA01, aA45 = aA01, aA67 = aA01; \
        __half2 aB01 = aA01, aB23 = aA01, aB45 = aA01, aB67 = aA01; \
        if (t_ < nf_)  { uint4 c_ = plF_[t_]; PROCA(c_.x); PROCA(c_.y); PROCA(c_.z); PROCA(c_.w); } \
        if (t_ < nbk_) { uint4 c_ = plB_[t_]; PROCB(c_.x); PROCB(c_.y); PROCB(c_.z); PROCB(c_.w); } \
        int t2_ = t_ + 1; \
        if (t2_ < nf_)  { uint4 c_ = plF_[t2_]; PROCA(c_.x); PROCA(c_.y); PROCA(c_.z); PROCA(c_.w); } \
        if (t2_ < nbk_) { uint4 c_ = plB_[t2_]; PROCB(c_.x); PROCB(c_.y); PROCB(c_.z); PROCB(c_.w); } \
        t_ += 2; \
        float2 u_; \
        u_ = __half22float2(aA01); f0 += u_.x; f1 += u_.y; \
        u_ = __half22float2(aA23); f2 += u_.x; f3 += u_.y; \
        u_ = __half22float2(aA45); f4 += u_.x; f5 += u_.y; \
        u_ = __half22float2(aA67); f6 += u_.x; f7 += u_.y; \
        u_ = __half22float2(aB01); f0 += u_.x; f1 += u_.y; \
        u_ = __half22float2(aB23); f2 += u_.x; f3 += u_.y; \
        u_ = __half22float2(aB45); f4 += u_.x; f5 += u_.y; \
        u_ = __half22float2(aB67); f6 += u_.x; f7 += u_.y; \
    } \
    /* stage 0: xor 8 */ \
    { float t0 = __shfl_xor(f1, 8, 64), t1 = __shfl_xor(f0, 8, 64); \
      float t2 = __shfl_xor(f3, 8, 64), t3 = __shfl_xor(f2, 8, 64); \
      float t4 = __shfl_xor(f5, 8, 64), t5 = __shfl_xor(f4, 8, 64); \
      float t6 = __shfl_xor(f7, 8, 64), t7 = __shfl_xor(f6, 8, 64); \
      f0 = h0 ? t0 : f0; f1 = h0 ? f1 : t1; f2 = h0 ? t2 : f2; f3 = h0 ? f3 : t3; \
      f4 = h0 ? t4 : f4; f5 = h0 ? f5 : t5; f6 = h0 ? t6 : f6; f7 = h0 ? f7 : t7; } \
    /* stage 1: xor 16 */ \
    { float t0 = __shfl_xor(f2, 16, 64), t1 = __shfl_xor(f3, 16, 64); \
      float t2 = __shfl_xor(f0, 16, 64), t3 = __shfl_xor(f1, 16, 64); \
      float t4 = __shfl_xor(f6, 16, 64), t5 = __shfl_xor(f7, 16, 64); \
      float t6 = __shfl_xor(f4, 16, 64), t7 = __shfl_xor(f5, 16, 64); \
      f0 = h1 ? t0 : f0; f1 = h1 ? t1 : f1; f2 = h1 ? f2 : t2; f3 = h1 ? f3 : t3; \
      f4 = h1 ? t4 : f4; f5 = h1 ? t5 : f5; f6 = h1 ? f6 : t6; f7 = h1 ? f7 : t7; } \
    /* stage 2: xor 32 */ \
    { float t0 = __shfl_xor(f4, 32, 64), t1 = __shfl_xor(f5, 32, 64); \
      float t2 = __shfl_xor(f6, 32, 64), t3 = __shfl_xor(f7, 32, 64); \
      float t4 = __shfl_xor(f0, 32, 64), t5 = __shfl_xor(f1, 32, 64); \
      float t6 = __shfl_xor(f2, 32, 64), t7 = __shfl_xor(f3, 32, 64); \
      f0 = h2 ? t0 : f0; f1 = h2 ? t1 : f1; f2 = h2 ? t2 : f2; f3 = h2 ? t3 : f3; \
      f4 = h2 ? f4 : t4; f5 = h2 ? f5 : t5; f6 = h2 ? f6 : t6; f7 = h2 ? f7 : t7; } \
    DST0 = make_float4(f0, f1, f2, f3); \
    DST1 = make_float4(f4, f5, f6, f7); }

__global__ __launch_bounds__(NTHREADS, 4)
void k_main(const float* __restrict__ b1, const float* __restrict__ b2,
            const float* __restrict__ s1, const float* __restrict__ s2,
            const int* __restrict__ cnt, const int* __restrict__ cntmax,
            const uint32_t* __restrict__ pairs, float* __restrict__ out) {
    __shared__ __align__(16) char xsh[LDSSZ];   // x2 (513 ch) + x1 (513 ch) @128B
    int bx = blockIdx.x;                   // 0..63 row-block
    int gy = blockIdx.y;                   // 0..3
    int r_base = bx * ROWS;
    int b = r_base >> 9;
    int w0 = r_base & (CBP_W - 1);
    int tid = threadIdx.x;

    // stage sign-folded f16, transposed [c][r] @128B stride; x2 at 0, x1 at X1OFF
    for (int u = tid; u < CBP_C * 8; u += NTHREADS) {
        int c = u >> 3;
        int r8 = (u & 7) << 3;
        size_t g = ((size_t)(b * CBP_C + c)) * CBP_W + w0 + r8;
        float4 u0 = *(const float4*)(b1 + g), u1 = *(const float4*)(b1 + g + 4);
        float4 v0 = *(const float4*)(b2 + g), v1 = *(const float4*)(b2 + g + 4);
        float sa = s1[c], sb = s2[c];
        union { __half2 h2[4]; uint4 q; } A, Bv;
        A.h2[0] = __floats2half2_rn(u0.x * sa, u0.y * sa);
        A.h2[1] = __floats2half2_rn(u0.z * sa, u0.w * sa);
        A.h2[2] = __floats2half2_rn(u1.x * sa, u1.y * sa);
        A.h2[3] = __floats2half2_rn(u1.z * sa, u1.w * sa);
        Bv.h2[0] = __floats2half2_rn(v0.x * sb, v0.y * sb);
        Bv.h2[1] = __floats2half2_rn(v0.z * sb, v0.w * sb);
        Bv.h2[2] = __floats2half2_rn(v1.x * sb, v1.y * sb);
        Bv.h2[3] = __floats2half2_rn(v1.z * sb, v1.w * sb);
        *(uint4*)(xsh + X1OFF + (c << 7) + (r8 << 1)) = A.q;
        *(uint4*)(xsh + (c << 7) + (r8 << 1)) = Bv.q;
    }
    if (tid < 16) {   // zero channels for both regions
        int z = tid & 7;
        char* p0 = (tid < 8) ? (xsh + ZREL) : (xsh + X1OFF + ZREL);
        *(uint4*)(p0 + z * 16) = make_uint4(0, 0, 0, 0);
    }
    __syncthreads();

    int wv = tid >> 6;                     // 0..15
    int lane = tid & 63;
    int grp = lane >> 3;                   // group: d within octet
    int l = lane & 7;                      // rows 8l..8l+7
    bool h0 = (grp & 1) != 0, h1 = (grp & 2) != 0, h2 = (grp & 4) != 0;
    uint32_t baseA = (uint32_t)(X1OFF + (l << 4));
    uint32_t baseB = (uint32_t)(l << 4);
    int dbase = gy * (CBP_D / NSPLIT) + wv * 128;   // wave owns 128 contiguous d's

    // cross-octet pipeline: octet-max + own count of the upcoming octet
    int nmax_cur = __builtin_amdgcn_readfirstlane(cntmax[dbase >> 3]) >> 2;
    int nown_cur = cnt[dbase + grp] >> 2;

    // after butterfly, lane stores row 8*(lane&7) + (lane>>3); 16 d (64B) burst
    int rrow = (l << 3) + grp;
    float* obase = out + (size_t)(r_base + rrow) * CBP_D + dbase;

    for (int oo = 0; oo < 8; ++oo) {
        float4 B0, B1, B2, B3;
        OCT(0, B0, B1); OCT(1, B2, B3);
        float* o_ = obase + (oo << 4);
        *(float4*)(o_)      = B0;
        *(float4*)(o_ + 4)  = B1;
        *(float4*)(o_ + 8)  = B2;
        *(float4*)(o_ + 12) = B3;
    }
}

// ================= launch =================

extern "C" void kernel_launch(void* const* d_in, const int* in_sizes, int n_in,
                              void* d_out, int out_size, void* d_ws, size_t ws_size,
                              hipStream_t stream) {
    const float* b1 = (const float*)d_in[0];
    const float* b2 = (const float*)d_in[1];
    const int*   h1 = (const int*)d_in[2];
    const float* s1 = (const float*)d_in[3];
    const int*   h2 = (const int*)d_in[4];
    const float* s2 = (const float*)d_in[5];
    float* out = (float*)d_out;

    int* cnt    = (int*)d_ws;                         // 8192
    int* cntmax = cnt + 8192;                         // 1024 (+ pad)
    uint32_t* pairs = (uint32_t*)(cntmax + 1024 + 8); // 8192*NCAP u32 (~2.6 MB)

    pB_fill<<<128, 512, 0, stream>>>(h1, h2, cnt, cntmax, pairs);

    dim3 g(CBP_W * 8 / ROWS, NSPLIT);     // (64, 4)
    k_main<<<g, NTHREADS, 0, stream>>>(b1, b2, s1, s2, cnt, cntmax, pairs, out);
}

// Round 18
// 129.232 us; speedup vs baseline: 1.0779x; 1.0779x over previous
//
#include <hip/hip_runtime.h>
#include <hip/hip_fp16.h>
#include <stdint.h>

#define CBP_D 8192
#define CBP_C 512
#define CBP_W 512
#define ROWS 64          // rows staged per block; lane covers 8 rows (b128)
#define NTHREADS 1024    // 16 waves
#define NSPLIT 4         // 64 row-blocks x 4 = 256 blocks = 1/CU
#define NCAP 80          // pair-list row capacity (20 uint4: allows unclamped +2 prefetch)

// LDS layout (bytes): 128B channel stride. x2 ch 0..512 (ch 512 = zeros),
// then x1 ch 0..512 (ch 512 = zeros). Pair word = (i<<7)|(j<<17).
#define X1OFF 65664      // 513*128
#define ZREL  65536      // zero channel offset within each region (ch 512)
#define LDSSZ 131328     // X1OFF + 513*128
#define PADW  ((512u << 7) | (512u << 17))   // pad: both sides hit zero channels

// ================= precompute (single fused kernel) =================
// 128 blocks x 512 threads; block rebuilds h2 buckets in LDS, then builds
// pair lists for its 64 d's with 8 threads per d. Per-d counts padded to
// multiple of 4 (pads -> zero channels); per-octet max in cntmax.
__global__ __launch_bounds__(512, 2)
void pB_fill(const int* __restrict__ h1, const int* __restrict__ h2,
             int* __restrict__ cnt, int* __restrict__ cntmax,
             uint32_t* __restrict__ pairs) {
    __shared__ int sc[CBP_D];       // h2 histogram
    __shared__ int sb[CBP_D];       // bucket start offsets
    __shared__ int ssum[512];
    __shared__ short sbk[CBP_C];    // bucket-ordered j list
    __shared__ int sh1[CBP_C];
    __shared__ int sh2[CBP_C];
    __shared__ int pc[64][8];
    __shared__ int rawt[64];
    int tid = threadIdx.x;          // 512

    for (int k = tid; k < CBP_D; k += 512) sc[k] = 0;
    sh1[tid] = h1[tid];
    sh2[tid] = h2[tid];
    __syncthreads();
    atomicAdd(&sc[sh2[tid]], 1);
    __syncthreads();
    int base = tid * 16;
    int loc[16]; int s = 0;
#pragma unroll
    for (int k = 0; k < 16; ++k) { loc[k] = sc[base + k]; s += loc[k]; }
    ssum[tid] = s;
    __syncthreads();
    int acc = s;
    for (int off = 1; off < 512; off <<= 1) {
        int add = (tid >= off) ? ssum[tid - off] : 0;
        __syncthreads();
        acc += add; ssum[tid] = acc;
        __syncthreads();
    }
    int excl = acc - s;
#pragma unroll
    for (int k = 0; k < 16; ++k) { sb[base + k] = excl; excl += loc[k]; }
    __syncthreads();
    {
        int h = sh2[tid]; int r = 0;
        for (int j2 = 0; j2 < tid; ++j2) r += (sh2[j2] == h);
        sbk[sb[h] + r] = (short)tid;
    }
    __syncthreads();

    // ---- pair-list build: 8 threads per d, 64 d's per block ----
    int dl = tid >> 3, p = tid & 7;
    int d = blockIdx.x * 64 + dl;
    int i0 = p << 6;
    int cp = 0;
#pragma unroll 4
    for (int i = i0; i < i0 + 64; ++i) cp += sc[(d - sh1[i]) & (CBP_D - 1)];
    pc[dl][p] = cp;
    __syncthreads();
    int off = 0, tot = 0;
#pragma unroll
    for (int p2 = 0; p2 < 8; ++p2) { int v = pc[dl][p2]; off += (p2 < p) ? v : 0; tot += v; }
    uint32_t* pd = pairs + (size_t)d * NCAP;
    int pos = off;
    for (int i = i0; i < i0 + 64; ++i) {
        int t = (d - sh1[i]) & (CBP_D - 1);
        int n = sc[t];
        if (n) {
            int bo = sb[t];
            uint32_t iw = (uint32_t)(i << 7);
            for (int k = 0; k < n; ++k)
                pd[pos++] = iw | ((uint32_t)sbk[bo + k] << 17);
        }
    }
    // pad own list to multiple of 4 (pads -> zero channels)
    int npad = (4 - (tot & 3)) & 3;
    if (p < npad) pd[tot + p] = PADW;
    if (p == 0) { rawt[dl] = tot; cnt[d] = (tot + 3) & ~3; }
    __syncthreads();
    if (p == 0 && (dl & 7) == 0) {
        int omax = 0;
#pragma unroll
        for (int z = 0; z < 8; ++z) omax = max(omax, rawt[dl + z]);
        cntmax[blockIdx.x * 8 + (dl >> 3)] = (omax + 3) & ~3;
    }
}

// ================= main =================

// Group grp (lane>>3) owns d = octb+grp; lane l (lane&7) covers rows 8l..8l+7
// via one ds_read_b128 per operand (128B aligned per group => bank-even).
#define PROC(P) { \
    uint32_t p_ = (P); \
    uint32_t aB_ = (p_ & 0x1FF80u) + baseA; \
    uint32_t bB_ = ((p_ >> 10) & 0x1FF80u) + baseB; \
    uint4 ra_ = *(const uint4*)(xsh + aB_); \
    uint4 rb_ = *(const uint4*)(xsh + bB_); \
    a01 = __hfma2(*(const __half2*)&ra_.x, *(const __half2*)&rb_.x, a01); \
    a23 = __hfma2(*(const __half2*)&ra_.y, *(const __half2*)&rb_.y, a23); \
    a45 = __hfma2(*(const __half2*)&ra_.z, *(const __half2*)&rb_.z, a45); \
    a67 = __hfma2(*(const __half2*)&ra_.w, *(const __half2*)&rb_.w, a67); }

// One octet (8 consecutive d). Loop bound = octet max (scalar); each group
// exec-masks its tail via its own count. Pair stream is 2-deep prefetched
// with NO clamp arithmetic (NCAP=80 row allows +2 over-read, values unused).
// After 3-stage butterfly, lane holds row 8*(lane&7)+(lane>>3), d octb+0..7.
#define OCT(K, DST0, DST1) { \
    int oc_ = (oo << 1) + (K); \
    int octb_ = dbase + (oc_ << 3); \
    int nbmax_ = nmax_cur; \
    int nbown_ = nown_cur; \
    uint4 c0_ = pp0_cur, c1_ = pp1_cur; \
    int no_ = (oc_ + 1 < 16) ? oc_ + 1 : 15; \
    int nmax_n_ = __builtin_amdgcn_readfirstlane(cntmax[(dbase >> 3) + no_]) >> 2; \
    int nown_n_ = cnt[dbase + (no_ << 3) + grp] >> 2; \
    const uint4* pl4n_ = (const uint4*)(pairs + (size_t)(dbase + (no_ << 3) + grp) * NCAP); \
    uint4 pp0n_ = pl4n_[0]; \
    uint4 pp1n_ = pl4n_[1]; \
    const uint4* pl4_ = (const uint4*)(pairs + (size_t)(octb_ + grp) * NCAP); \
    float f0 = 0.f, f1 = 0.f, f2 = 0.f, f3 = 0.f; \
    float f4 = 0.f, f5 = 0.f, f6 = 0.f, f7 = 0.f; \
    int t4_ = 0; \
    while (t4_ < nbmax_) { \
        __half2 a01 = __floats2half2_rn(0.f, 0.f); \
        __half2 a23 = a01, a45 = a01, a67 = a01; \
        int ce_ = (t4_ + 4 < nbmax_) ? t4_ + 4 : nbmax_; \
        for (; t4_ < ce_; ++t4_) { \
            if (t4_ < nbown_) { \
                uint4 c_ = c0_; \
                c0_ = c1_; \
                c1_ = pl4_[t4_ + 2];   /* unclamped: row has 20 uint4 */ \
                PROC(c_.x); PROC(c_.y); PROC(c_.z); PROC(c_.w); \
            } \
        } \
        float2 u_; \
        u_ = __half22float2(a01); f0 += u_.x; f1 += u_.y; \
        u_ = __half22float2(a23); f2 += u_.x; f3 += u_.y; \
        u_ = __half22float2(a45); f4 += u_.x; f5 += u_.y; \
        u_ = __half22float2(a67); f6 += u_.x; f7 += u_.y; \
    } \
    nmax_cur = nmax_n_; nown_cur = nown_n_; \
    pp0_cur = pp0n_; pp1_cur = pp1n_; \
    /* stage 0: xor 8 */ \
    { float t0 = __shfl_xor(f1, 8, 64), t1 = __shfl_xor(f0, 8, 64); \
      float t2 = __shfl_xor(f3, 8, 64), t3 = __shfl_xor(f2, 8, 64); \
      float t4 = __shfl_xor(f5, 8, 64), t5 = __shfl_xor(f4, 8, 64); \
      float t6 = __shfl_xor(f7, 8, 64), t7 = __shfl_xor(f6, 8, 64); \
      f0 = h0 ? t0 : f0; f1 = h0 ? f1 : t1; f2 = h0 ? t2 : f2; f3 = h0 ? f3 : t3; \
      f4 = h0 ? t4 : f4; f5 = h0 ? f5 : t5; f6 = h0 ? t6 : f6; f7 = h0 ? f7 : t7; } \
    /* stage 1: xor 16 */ \
    { float t0 = __shfl_xor(f2, 16, 64), t1 = __shfl_xor(f3, 16, 64); \
      float t2 = __shfl_xor(f0, 16, 64), t3 = __shfl_xor(f1, 16, 64); \
      float t4 = __shfl_xor(f6, 16, 64), t5 = __shfl_xor(f7, 16, 64); \
      float t6 = __shfl_xor(f4, 16, 64), t7 = __shfl_xor(f5, 16, 64); \
      f0 = h1 ? t0 : f0; f1 = h1 ? t1 : f1; f2 = h1 ? f2 : t2; f3 = h1 ? f3 : t3; \
      f4 = h1 ? t4 : f4; f5 = h1 ? t5 : f5; f6 = h1 ? f6 : t6; f7 = h1 ? f7 : t7; } \
    /* stage 2: xor 32 */ \
    { float t0 = __shfl_xor(f4, 32, 64), t1 = __shfl_xor(f5, 32, 64); \
      float t2 = __shfl_xor(f6, 32, 64), t3 = __shfl_xor(f7, 32, 64); \
      float t4 = __shfl_xor(f0, 32, 64), t5 = __shfl_xor(f1, 32, 64); \
      float t6 = __shfl_xor(f2, 32, 64), t7 = __shfl_xor(f3, 32, 64); \
      f0 = h2 ? t0 : f0; f1 = h2 ? t1 : f1; f2 = h2 ? t2 : f2; f3 = h2 ? t3 : f3; \
      f4 = h2 ? f4 : t4; f5 = h2 ? f5 : t5; f6 = h2 ? f6 : t6; f7 = h2 ? f7 : t7; } \
    DST0 = make_float4(f0, f1, f2, f3); \
    DST1 = make_float4(f4, f5, f6, f7); }

__global__ __launch_bounds__(NTHREADS, 4)
void k_main(const float* __restrict__ b1, const float* __restrict__ b2,
            const float* __restrict__ s1, const float* __restrict__ s2,
            const int* __restrict__ cnt, const int* __restrict__ cntmax,
            const uint32_t* __restrict__ pairs, float* __restrict__ out) {
    __shared__ __align__(16) char xsh[LDSSZ];   // x2 (513 ch) + x1 (513 ch) @128B
    int bx = blockIdx.x;                   // 0..63 row-block
    int gy = blockIdx.y;                   // 0..3
    int r_base = bx * ROWS;
    int b = r_base >> 9;
    int w0 = r_base & (CBP_W - 1);
    int tid = threadIdx.x;

    // stage sign-folded f16, transposed [c][r] @128B stride; x2 at 0, x1 at X1OFF
    for (int u = tid; u < CBP_C * 8; u += NTHREADS) {
        int c = u >> 3;
        int r8 = (u & 7) << 3;
        size_t g = ((size_t)(b * CBP_C + c)) * CBP_W + w0 + r8;
        float4 u0 = *(const float4*)(b1 + g), u1 = *(const float4*)(b1 + g + 4);
        float4 v0 = *(const float4*)(b2 + g), v1 = *(const float4*)(b2 + g + 4);
        float sa = s1[c], sb = s2[c];
        union { __half2 h2[4]; uint4 q; } A, Bv;
        A.h2[0] = __floats2half2_rn(u0.x * sa, u0.y * sa);
        A.h2[1] = __floats2half2_rn(u0.z * sa, u0.w * sa);
        A.h2[2] = __floats2half2_rn(u1.x * sa, u1.y * sa);
        A.h2[3] = __floats2half2_rn(u1.z * sa, u1.w * sa);
        Bv.h2[0] = __floats2half2_rn(v0.x * sb, v0.y * sb);
        Bv.h2[1] = __floats2half2_rn(v0.z * sb, v0.w * sb);
        Bv.h2[2] = __floats2half2_rn(v1.x * sb, v1.y * sb);
        Bv.h2[3] = __floats2half2_rn(v1.z * sb, v1.w * sb);
        *(uint4*)(xsh + X1OFF + (c << 7) + (r8 << 1)) = A.q;
        *(uint4*)(xsh + (c << 7) + (r8 << 1)) = Bv.q;
    }
    if (tid < 16) {   // zero channels for both regions
        int z = tid & 7;
        char* p0 = (tid < 8) ? (xsh + ZREL) : (xsh + X1OFF + ZREL);
        *(uint4*)(p0 + z * 16) = make_uint4(0, 0, 0, 0);
    }
    __syncthreads();

    int wv = tid >> 6;                     // 0..15
    int lane = tid & 63;
    int grp = lane >> 3;                   // group: d within octet
    int l = lane & 7;                      // rows 8l..8l+7
    bool h0 = (grp & 1) != 0, h1 = (grp & 2) != 0, h2 = (grp & 4) != 0;
    uint32_t baseA = (uint32_t)(X1OFF + (l << 4));
    uint32_t baseB = (uint32_t)(l << 4);
    int dbase = gy * (CBP_D / NSPLIT) + wv * 128;   // wave owns 128 contiguous d's

    // cross-octet pipeline: octet-max, own count, first TWO uint4s of next octet
    int nmax_cur = __builtin_amdgcn_readfirstlane(cntmax[dbase >> 3]) >> 2;
    int nown_cur = cnt[dbase + grp] >> 2;
    const uint4* pl40 = (const uint4*)(pairs + (size_t)(dbase + grp) * NCAP);
    uint4 pp0_cur = pl40[0];
    uint4 pp1_cur = pl40[1];

    // after butterfly, lane stores row 8*(lane&7) + (lane>>3); 16 d (64B) burst
    int rrow = (l << 3) + grp;
    float* obase = out + (size_t)(r_base + rrow) * CBP_D + dbase;

    for (int oo = 0; oo < 8; ++oo) {
        float4 B0, B1, B2, B3;
        OCT(0, B0, B1); OCT(1, B2, B3);
        float* o_ = obase + (oo << 4);
        *(float4*)(o_)      = B0;
        *(float4*)(o_ + 4)  = B1;
        *(float4*)(o_ + 8)  = B2;
        *(float4*)(o_ + 12) = B3;
    }
}

// ================= launch =================

extern "C" void kernel_launch(void* const* d_in, const int* in_sizes, int n_in,
                              void* d_out, int out_size, void* d_ws, size_t ws_size,
                              hipStream_t stream) {
    const float* b1 = (const float*)d_in[0];
    const float* b2 = (const float*)d_in[1];
    const int*   h1 = (const int*)d_in[2];
    const float* s1 = (const float*)d_in[3];
    const int*   h2 = (const int*)d_in[4];
    const float* s2 = (const float*)d_in[5];
    float* out = (float*)d_out;

    int* cnt    = (int*)d_ws;                         // 8192
    int* cntmax = cnt + 8192;                         // 1024 (+ pad)
    uint32_t* pairs = (uint32_t*)(cntmax + 1024 + 8); // 8192*NCAP u32 (~2.6 MB)

    pB_fill<<<128, 512, 0, stream>>>(h1, h2, cnt, cntmax, pairs);

    dim3 g(CBP_W * 8 / ROWS, NSPLIT);     // (64, 4)
    k_main<<<g, NTHREADS, 0, stream>>>(b1, b2, s1, s2, cnt, cntmax, pairs, out);
}